// Round 1
// baseline (718.040 us; speedup 1.0000x reference)
//
#include <hip/hip_runtime.h>
#include <math.h>

// Problem constants
static const int kB = 32;
static const int kL = 1024;
static const int kH = 512;
static const int kN = 64;
static const int kNL = 4;
static const int kNFFT = 2048;

#define PI_F 3.14159265358979323846f
#define TWO_PI 6.283185307179586476925286766559

__device__ __forceinline__ float2 cmul(float2 a, float2 b) {
    return make_float2(a.x * b.x - a.y * b.y, a.x * b.y + a.y * b.x);
}

__device__ __forceinline__ float gelu_tanh(float v) {
    // jax.nn.gelu default (approximate=True)
    float v3 = v * v * v;
    return 0.5f * v * (1.0f + tanhf(0.7978845608028654f * (v + 0.044715f * v3)));
}

// ---------------------------------------------------------------------------
// In-LDS 2048-point complex FFT, radix-2 Stockham (auto-sort, no bit reverse).
// 256 threads, 4 butterflies each per stage, 11 stages.
// Wtab[i] = exp(-2*pi*i*i/2048), i in [0,1024).
// Returns pointer to the buffer holding the result (arg2, since 11 is odd).
// ---------------------------------------------------------------------------
__device__ float2* fft2048(float2* __restrict__ bufA, float2* __restrict__ bufB,
                           const float2* __restrict__ Wtab, bool inverse, int tid)
{
    float2* src = bufA;
    float2* dst = bufB;
    for (int lgm = 0; lgm < 11; ++lgm) {
        int m = 1 << lgm;
#pragma unroll
        for (int p = 0; p < 4; ++p) {
            int q  = tid + (p << 8);
            int jm = q & ~(m - 1);
            float2 c0 = src[q];
            float2 c1 = src[q + 1024];
            float2 w  = Wtab[jm];
            if (inverse) w.y = -w.y;
            float2 s = make_float2(c0.x + c1.x, c0.y + c1.y);
            float2 d = make_float2(c0.x - c1.x, c0.y - c1.y);
            dst[q + jm]     = s;
            dst[q + jm + m] = cmul(w, d);
        }
        __syncthreads();
        float2* t = src; src = dst; dst = t;
    }
    return src;
}

// ---------------------------------------------------------------------------
// Twiddle table
// ---------------------------------------------------------------------------
__global__ void twiddle_kernel(float2* __restrict__ Wtab)
{
    int i = blockIdx.x * 256 + threadIdx.x;
    if (i < 1024) {
        double ang = -TWO_PI * (double)i / 2048.0;
        Wtab[i] = make_float2((float)cos(ang), (float)sin(ang));
    }
}

// ---------------------------------------------------------------------------
// Embedding gather with 64x64 tile transpose: act[b][h][l] = emb[x[b][l]][h]
// grid: (hb=8, lb=16, b=32), 256 threads
// ---------------------------------------------------------------------------
__global__ __launch_bounds__(256) void embed_kernel(const int* __restrict__ x,
                                                    const float* __restrict__ emb,
                                                    float* __restrict__ act)
{
    __shared__ float tile[64][65];
    int hb = blockIdx.x, lb = blockIdx.y, b = blockIdx.z;
    int h0 = hb * 64, l0 = lb * 64;
    int tid = threadIdx.x;
#pragma unroll
    for (int k = 0; k < 16; ++k) {
        int idx = (k << 8) + tid;
        int li = idx >> 6, hi = idx & 63;
        int xv = x[b * kL + l0 + li];
        tile[li][hi] = emb[(size_t)xv * kH + h0 + hi];
    }
    __syncthreads();
#pragma unroll
    for (int k = 0; k < 16; ++k) {
        int idx = (k << 8) + tid;
        int hi = idx >> 6, li = idx & 63;
        act[((size_t)b * kH + h0 + hi) * kL + l0 + li] = tile[li][hi];
    }
}

// ---------------------------------------------------------------------------
// Per-layer SSM kernel K[h][l] + its 2048-pt FFT -> Khat[h][0..2047]
// grid: 512 (one per h), 256 threads
// ---------------------------------------------------------------------------
__global__ __launch_bounds__(256) void kcomp_kernel(const float* __restrict__ log_dt,
                                                    const float* __restrict__ A_log,
                                                    const float* __restrict__ A_imag,
                                                    const float* __restrict__ C_re,
                                                    const float* __restrict__ C_im,
                                                    float2* __restrict__ Khat,
                                                    const float2* __restrict__ Wtab)
{
    __shared__ float2 bufA[kNFFT];
    __shared__ float2 bufB[kNFFT];
    __shared__ float dre_s[kN], dim_s[kN], g2re_s[kN], g2im_s[kN];

    int h = blockIdx.x, tid = threadIdx.x;

    if (tid < kN) {
        int n = tid;
        float dt  = expf(log_dt[h]);
        float Are = -expf(A_log[h * kN + n]);
        float Aim = A_imag[h * kN + n];
        float dre = dt * Are;
        float dim = dt * Aim;
        float er = expf(dre);
        float sw, cw;
        sincosf(dim, &sw, &cw);
        float2 e   = make_float2(er * cw, er * sw);
        float2 em1 = make_float2(e.x - 1.0f, e.y);
        float inv  = 1.0f / (Are * Are + Aim * Aim);
        float2 Ainv = make_float2(Are * inv, -Aim * inv);
        float2 C = make_float2(C_re[h * kN + n], C_im[h * kN + n]);
        float2 Ct = cmul(C, cmul(em1, Ainv));
        dre_s[n] = dre;
        dim_s[n] = dim;
        g2re_s[n] = 2.0f * Ct.x;
        g2im_s[n] = 2.0f * Ct.y;
    }
    __syncthreads();

    // Each thread computes K[l] for 4 consecutive l.
    float acc0 = 0.f, acc1 = 0.f, acc2 = 0.f, acc3 = 0.f;
    int l0 = tid * 4;
    for (int n = 0; n < kN; ++n) {
        float dre = dre_s[n], dim = dim_s[n];
        float g2re = g2re_s[n], g2im = g2im_s[n];
        // per-mode step w = exp(dre + i*dim)
        float erw = expf(dre);
        float swv, cwv;
        sincosf(dim, &swv, &cwv);
        float2 w = make_float2(erw * cwv, erw * swv);
        // p = exp((dre + i*dim) * l0); reduce phase through a double for accuracy
        float mag = expf(dre * (float)l0);
        double rev = (double)dim * (double)l0 * (1.0 / TWO_PI);
        rev -= floor(rev);
        float th = (float)(rev * TWO_PI);
        float sp, cp;
        sincosf(th, &sp, &cp);
        float2 pz = make_float2(mag * cp, mag * sp);

        acc0 += g2re * pz.x - g2im * pz.y; pz = cmul(pz, w);
        acc1 += g2re * pz.x - g2im * pz.y; pz = cmul(pz, w);
        acc2 += g2re * pz.x - g2im * pz.y; pz = cmul(pz, w);
        acc3 += g2re * pz.x - g2im * pz.y;
    }
    bufA[l0 + 0] = make_float2(acc0, 0.f);
    bufA[l0 + 1] = make_float2(acc1, 0.f);
    bufA[l0 + 2] = make_float2(acc2, 0.f);
    bufA[l0 + 3] = make_float2(acc3, 0.f);
    bufA[1024 + l0 + 0] = make_float2(0.f, 0.f);
    bufA[1024 + l0 + 1] = make_float2(0.f, 0.f);
    bufA[1024 + l0 + 2] = make_float2(0.f, 0.f);
    bufA[1024 + l0 + 3] = make_float2(0.f, 0.f);
    __syncthreads();

    float2* R = fft2048(bufA, bufB, Wtab, false, tid);
    float2* outp = Khat + (size_t)h * kNFFT;
#pragma unroll
    for (int p = 0; p < 8; ++p) {
        int k = tid + (p << 8);
        outp[k] = R[k];
    }
}

// ---------------------------------------------------------------------------
// Conv layer (in-place): per wg handles rows (2*pair,h) and (2*pair+1,h),
// packed as one complex signal. FFT -> *Khat -> IFFT -> +D*u -> gelu.
// grid: (h=512, pair=16), 256 threads
// ---------------------------------------------------------------------------
__global__ __launch_bounds__(256) void conv_kernel(float* __restrict__ act,
                                                   const float2* __restrict__ Khat,
                                                   const float2* __restrict__ Wtab,
                                                   const float* __restrict__ Dvec)
{
    __shared__ float2 bufA[kNFFT];
    __shared__ float2 bufB[kNFFT];
    __shared__ float2 usave[kL];

    int h = blockIdx.x, pair = blockIdx.y, tid = threadIdx.x;
    float* rowa = act + ((size_t)(2 * pair)     * kH + h) * kL;
    float* rowb = act + ((size_t)(2 * pair + 1) * kH + h) * kL;

#pragma unroll
    for (int p = 0; p < 4; ++p) {
        int l = tid + (p << 8);
        float2 z = make_float2(rowa[l], rowb[l]);
        bufA[l] = z;
        usave[l] = z;
        bufA[l + 1024] = make_float2(0.f, 0.f);
    }
    __syncthreads();

    float2* Zs = fft2048(bufA, bufB, Wtab, false, tid);

    const float2* kh = Khat + (size_t)h * kNFFT;
#pragma unroll
    for (int p = 0; p < 8; ++p) {
        int k = tid + (p << 8);
        Zs[k] = cmul(Zs[k], kh[k]);
    }
    __syncthreads();

    float2* other = (Zs == bufA) ? bufB : bufA;
    float2* Ys = fft2048(Zs, other, Wtab, true, tid);

    float Dh = Dvec[h];
    const float invn = 1.0f / (float)kNFFT;
#pragma unroll
    for (int p = 0; p < 4; ++p) {
        int l = tid + (p << 8);
        float2 u = usave[l];
        float va = Ys[l].x * invn + Dh * u.x;
        float vb = Ys[l].y * invn + Dh * u.y;
        rowa[l] = gelu_tanh(va);
        rowb[l] = gelu_tanh(vb);
    }
}

// ---------------------------------------------------------------------------
// Mean pool over L + fc. grid: (hb=16, b=32), 256 threads; atomicAdd partials.
// ---------------------------------------------------------------------------
__global__ __launch_bounds__(256) void final_kernel(const float* __restrict__ act,
                                                    const float* __restrict__ fc_w,
                                                    const float* __restrict__ fc_b,
                                                    float* __restrict__ out)
{
    int hb = blockIdx.x, b = blockIdx.y, tid = threadIdx.x;
    float acc = 0.f;
    for (int hh = 0; hh < 32; ++hh) {
        int h = hb * 32 + hh;
        float w = fc_w[h];
        const float* row = act + ((size_t)b * kH + h) * kL;
#pragma unroll
        for (int l = tid; l < kL; l += 256) acc += row[l] * w;
    }
    __shared__ float red[256];
    red[tid] = acc;
    __syncthreads();
    for (int s = 128; s > 0; s >>= 1) {
        if (tid < s) red[tid] += red[tid + s];
        __syncthreads();
    }
    if (tid == 0) {
        float v = red[0] * (1.0f / (float)kL);
        if (hb == 0) v += fc_b[0];
        atomicAdd(out + b, v);
    }
}

// ---------------------------------------------------------------------------
extern "C" void kernel_launch(void* const* d_in, const int* in_sizes, int n_in,
                              void* d_out, int out_size, void* d_ws, size_t ws_size,
                              hipStream_t stream)
{
    const int*   x         = (const int*)d_in[0];
    const float* embedding = (const float*)d_in[1];
    const float* log_dt    = (const float*)d_in[2];
    const float* A_log     = (const float*)d_in[3];
    const float* A_imag    = (const float*)d_in[4];
    const float* C_re      = (const float*)d_in[5];
    const float* C_im      = (const float*)d_in[6];
    const float* Dv        = (const float*)d_in[7];
    const float* fc_w      = (const float*)d_in[8];
    const float* fc_b      = (const float*)d_in[9];
    float* out = (float*)d_out;

    char* ws = (char*)d_ws;
    const size_t act_bytes  = (size_t)kB * kH * kL * sizeof(float);   // 64 MiB
    const size_t khat_bytes = (size_t)kH * kNFFT * sizeof(float2);    // 8 MiB
    float*  act  = (float*)ws;
    float2* Khat = (float2*)(ws + act_bytes);
    float2* Wtab = (float2*)(ws + act_bytes + khat_bytes);

    hipMemsetAsync(d_out, 0, (size_t)out_size * sizeof(float), stream);
    twiddle_kernel<<<4, 256, 0, stream>>>(Wtab);
    embed_kernel<<<dim3(8, 16, 32), 256, 0, stream>>>(x, embedding, act);

    for (int layer = 0; layer < kNL; ++layer) {
        kcomp_kernel<<<kH, 256, 0, stream>>>(log_dt + layer * kH,
                                             A_log + (size_t)layer * kH * kN,
                                             A_imag + (size_t)layer * kH * kN,
                                             C_re + (size_t)layer * kH * kN,
                                             C_im + (size_t)layer * kH * kN,
                                             Khat, Wtab);
        conv_kernel<<<dim3(kH, kB / 2), 256, 0, stream>>>(act, Khat, Wtab, Dv + layer * kH);
    }

    final_kernel<<<dim3(16, kB), 256, 0, stream>>>(act, fc_w, fc_b, out);
}

// Round 2
// 479.093 us; speedup vs baseline: 1.4987x; 1.4987x over previous
//
#include <hip/hip_runtime.h>
#include <math.h>

// Problem constants
static const int kB = 32;
static const int kL = 1024;
static const int kH = 512;
static const int kN = 64;
static const int kNL = 4;
static const int kNFFT = 2048;

#define TWO_PI 6.283185307179586476925286766559

__device__ __forceinline__ float2 cmul(float2 a, float2 b) {
    return make_float2(a.x * b.x - a.y * b.y, a.x * b.y + a.y * b.x);
}
__device__ __forceinline__ float2 cadd(float2 a, float2 b) { return make_float2(a.x + b.x, a.y + b.y); }
__device__ __forceinline__ float2 csub(float2 a, float2 b) { return make_float2(a.x - b.x, a.y - b.y); }

__device__ __forceinline__ float gelu_tanh(float v) {
    float v3 = v * v * v;
    return 0.5f * v * (1.0f + tanhf(0.7978845608028654f * (v + 0.044715f * v3)));
}

// LDS swizzle: pad 1 float2 per 16 -> all stage access patterns land 4 lanes
// per bank-pair (the b64 optimum on 32x4B banks).
#define SW(i) ((i) + ((i) >> 4))
// max index SW(2047) = 2174
#define LDSZ 2176

// ---------------------------------------------------------------------------
// 8-point DFT in registers, natural order in/out. INV=true -> conjugate.
// ---------------------------------------------------------------------------
template<bool INV>
__device__ __forceinline__ void dft8(const float2 c[8], float2 y[8]) {
    const float s = 0.70710678118654752440f;
    // evens: c0,c2,c4,c6
    float2 t0 = cadd(c[0], c[4]), t1 = csub(c[0], c[4]);
    float2 t2 = cadd(c[2], c[6]), t3 = csub(c[2], c[6]);
    float2 e0 = cadd(t0, t2), e2 = csub(t0, t2);
    float2 e1, e3;
    if (!INV) { e1 = make_float2(t1.x + t3.y, t1.y - t3.x); e3 = make_float2(t1.x - t3.y, t1.y + t3.x); }
    else      { e1 = make_float2(t1.x - t3.y, t1.y + t3.x); e3 = make_float2(t1.x + t3.y, t1.y - t3.x); }
    // odds: c1,c3,c5,c7
    t0 = cadd(c[1], c[5]); t1 = csub(c[1], c[5]);
    t2 = cadd(c[3], c[7]); t3 = csub(c[3], c[7]);
    float2 o0 = cadd(t0, t2), o2 = csub(t0, t2);
    float2 o1, o3;
    if (!INV) { o1 = make_float2(t1.x + t3.y, t1.y - t3.x); o3 = make_float2(t1.x - t3.y, t1.y + t3.x); }
    else      { o1 = make_float2(t1.x - t3.y, t1.y + t3.x); o3 = make_float2(t1.x + t3.y, t1.y - t3.x); }
    // odd outputs times W8^u (conj if INV)
    if (!INV) {
        o1 = make_float2(s * (o1.x + o1.y), s * (o1.y - o1.x));
        o2 = make_float2(o2.y, -o2.x);
        o3 = make_float2(s * (o3.y - o3.x), -s * (o3.x + o3.y));
    } else {
        o1 = make_float2(s * (o1.x - o1.y), s * (o1.x + o1.y));
        o2 = make_float2(-o2.y, o2.x);
        o3 = make_float2(-s * (o3.x + o3.y), s * (o3.x - o3.y));
    }
    y[0] = cadd(e0, o0); y[4] = csub(e0, o0);
    y[1] = cadd(e1, o1); y[5] = csub(e1, o1);
    y[2] = cadd(e2, o2); y[6] = csub(e2, o2);
    y[3] = cadd(e3, o3); y[7] = csub(e3, o3);
}

// Stockham radix-8 stage output: dst[j*8m + i + u*m] = W_N^{jm*u} * y_u,
// jm = tid & ~(m-1). Twiddle via sincosf (|ang| < 0.79) + power chain.
template<bool INV>
__device__ __forceinline__ void stage8_write(float2* lds, int tid, int lgm, float2 y[8]) {
    const int m = 1 << lgm;
    const int jm = tid & ~(m - 1);
    float ang = (INV ? (float)(TWO_PI / 2048.0) : -(float)(TWO_PI / 2048.0)) * (float)jm;
    float sn, cs;
    sincosf(ang, &sn, &cs);
    float2 w1 = make_float2(cs, sn);
    float2 w2 = cmul(w1, w1);
    float2 w3 = cmul(w2, w1);
    float2 w4 = cmul(w2, w2);
    float2 w5 = cmul(w3, w2);
    float2 w6 = cmul(w3, w3);
    float2 w7 = cmul(w4, w3);
    const int base = ((tid >> lgm) << (lgm + 3)) + (tid & (m - 1));
    lds[SW(base        )] = y[0];
    lds[SW(base + 1 * m)] = cmul(w1, y[1]);
    lds[SW(base + 2 * m)] = cmul(w2, y[2]);
    lds[SW(base + 3 * m)] = cmul(w3, y[3]);
    lds[SW(base + 4 * m)] = cmul(w4, y[4]);
    lds[SW(base + 5 * m)] = cmul(w5, y[5]);
    lds[SW(base + 6 * m)] = cmul(w6, y[6]);
    lds[SW(base + 7 * m)] = cmul(w7, y[7]);
}

__device__ __forceinline__ void read8(const float2* lds, int tid, float2 c[8]) {
#pragma unroll
    for (int s = 0; s < 8; ++s) c[s] = lds[SW(tid + (s << 8))];
}

// ---------------------------------------------------------------------------
// Embedding gather with 64x64 tile transpose: act[b][h][l] = emb[x[b][l]][h]
// ---------------------------------------------------------------------------
__global__ __launch_bounds__(256) void embed_kernel(const int* __restrict__ x,
                                                    const float* __restrict__ emb,
                                                    float* __restrict__ act)
{
    __shared__ float tile[64][65];
    int hb = blockIdx.x, lb = blockIdx.y, b = blockIdx.z;
    int h0 = hb * 64, l0 = lb * 64;
    int tid = threadIdx.x;
#pragma unroll
    for (int k = 0; k < 16; ++k) {
        int idx = (k << 8) + tid;
        int li = idx >> 6, hi = idx & 63;
        int xv = x[b * kL + l0 + li];
        tile[li][hi] = emb[(size_t)xv * kH + h0 + hi];
    }
    __syncthreads();
#pragma unroll
    for (int k = 0; k < 16; ++k) {
        int idx = (k << 8) + tid;
        int hi = idx >> 6, li = idx & 63;
        act[((size_t)b * kH + h0 + hi) * kL + l0 + li] = tile[li][hi];
    }
}

// ---------------------------------------------------------------------------
// Per-layer SSM kernel K[h][l] + forward FFT -> Khat[h][0..2047] (natural order)
// grid: 512, 256 threads
// ---------------------------------------------------------------------------
__global__ __launch_bounds__(256) void kcomp_kernel(const float* __restrict__ log_dt,
                                                    const float* __restrict__ A_log,
                                                    const float* __restrict__ A_imag,
                                                    const float* __restrict__ C_re,
                                                    const float* __restrict__ C_im,
                                                    float2* __restrict__ Khat)
{
    __shared__ float2 lds[LDSZ];
    __shared__ float dre_s[kN], dim_s[kN], g2re_s[kN], g2im_s[kN];

    int h = blockIdx.x, tid = threadIdx.x;

    if (tid < kN) {
        int n = tid;
        float dt  = expf(log_dt[h]);
        float Are = -expf(A_log[h * kN + n]);
        float Aim = A_imag[h * kN + n];
        float dre = dt * Are;
        float dim = dt * Aim;
        float er = expf(dre);
        float sw, cw;
        sincosf(dim, &sw, &cw);
        float2 em1 = make_float2(er * cw - 1.0f, er * sw);
        float inv  = 1.0f / (Are * Are + Aim * Aim);
        float2 Ainv = make_float2(Are * inv, -Aim * inv);
        float2 C = make_float2(C_re[h * kN + n], C_im[h * kN + n]);
        float2 Ct = cmul(C, cmul(em1, Ainv));
        dre_s[n] = dre;
        dim_s[n] = dim;
        g2re_s[n] = 2.0f * Ct.x;
        g2im_s[n] = 2.0f * Ct.y;
    }
    __syncthreads();

    // K at l = tid + 256*s, s=0..3 (matches FFT stage-1 register layout)
    float acc0 = 0.f, acc1 = 0.f, acc2 = 0.f, acc3 = 0.f;
    for (int n = 0; n < kN; ++n) {
        float dre = dre_s[n], dim = dim_s[n];
        float g2re = g2re_s[n], g2im = g2im_s[n];
        // pz = exp((dre+i*dim)*tid), phase reduced through double
        float mag = expf(dre * (float)tid);
        double rev = (double)dim * (double)tid * (1.0 / TWO_PI);
        rev -= floor(rev);
        float th = (float)(rev * TWO_PI);
        float sp, cp;
        sincosf(th, &sp, &cp);
        float2 pz = make_float2(mag * cp, mag * sp);
        // w256 = exp((dre+i*dim)*256)
        float mag256 = expf(dre * 256.0f);
        double rev2 = (double)dim * 256.0 * (1.0 / TWO_PI);
        rev2 -= floor(rev2);
        float th2 = (float)(rev2 * TWO_PI);
        float s2, c2;
        sincosf(th2, &s2, &c2);
        float2 w256 = make_float2(mag256 * c2, mag256 * s2);

        acc0 += g2re * pz.x - g2im * pz.y; pz = cmul(pz, w256);
        acc1 += g2re * pz.x - g2im * pz.y; pz = cmul(pz, w256);
        acc2 += g2re * pz.x - g2im * pz.y; pz = cmul(pz, w256);
        acc3 += g2re * pz.x - g2im * pz.y;
    }

    // forward FFT: stage 1 from registers (upper half zero)
    {
        float2 c[8], y[8];
        c[0] = make_float2(acc0, 0.f); c[1] = make_float2(acc1, 0.f);
        c[2] = make_float2(acc2, 0.f); c[3] = make_float2(acc3, 0.f);
        c[4] = c[5] = c[6] = c[7] = make_float2(0.f, 0.f);
        dft8<false>(c, y);
        stage8_write<false>(lds, tid, 0, y);
    }
    __syncthreads();
    {
        float2 c[8], y[8];
        read8(lds, tid, c);
        __syncthreads();
        dft8<false>(c, y);
        stage8_write<false>(lds, tid, 3, y);
    }
    __syncthreads();
    {
        float2 c[8], y[8];
        read8(lds, tid, c);
        __syncthreads();
        dft8<false>(c, y);
        stage8_write<false>(lds, tid, 6, y);
    }
    __syncthreads();
    // radix-4 final stage (m=512, j=0, no twiddle) -> global, natural order
    {
        float2 cc[2][4];
#pragma unroll
        for (int r = 0; r < 2; ++r)
#pragma unroll
            for (int s = 0; s < 4; ++s)
                cc[r][s] = lds[SW(tid + (r << 8) + (s << 9))];
        float2* outp = Khat + (size_t)h * kNFFT;
#pragma unroll
        for (int r = 0; r < 2; ++r) {
            int q = tid + (r << 8);
            float2 t0 = cadd(cc[r][0], cc[r][2]), t1 = csub(cc[r][0], cc[r][2]);
            float2 t2 = cadd(cc[r][1], cc[r][3]), t3 = csub(cc[r][1], cc[r][3]);
            outp[q]        = cadd(t0, t2);
            outp[q + 512]  = make_float2(t1.x + t3.y, t1.y - t3.x);
            outp[q + 1024] = csub(t0, t2);
            outp[q + 1536] = make_float2(t1.x - t3.y, t1.y + t3.x);
        }
    }
}

// ---------------------------------------------------------------------------
// Conv layer (in-place): rows (2*pair,h),(2*pair+1,h) packed as one complex
// signal. Register radix-8 FFT, fused pointwise, fused epilogue.
// grid: (h=512, pair=16), 256 threads
// ---------------------------------------------------------------------------
__global__ __launch_bounds__(256) void conv_kernel(float* __restrict__ act,
                                                   const float2* __restrict__ Khat,
                                                   const float* __restrict__ Dvec)
{
    __shared__ float2 lds[LDSZ];

    int h = blockIdx.x, pair = blockIdx.y, tid = threadIdx.x;
    float* rowa = act + ((size_t)(2 * pair)     * kH + h) * kL;
    float* rowb = act + ((size_t)(2 * pair + 1) * kH + h) * kL;

    float2 us[4];
#pragma unroll
    for (int s = 0; s < 4; ++s) {
        int l = tid + (s << 8);
        us[s] = make_float2(rowa[l], rowb[l]);
    }

    // ---- forward stage 1 (m=1), upper half zero ----
    {
        float2 c[8], y[8];
#pragma unroll
        for (int s = 0; s < 4; ++s) { c[s] = us[s]; c[s + 4] = make_float2(0.f, 0.f); }
        dft8<false>(c, y);
        stage8_write<false>(lds, tid, 0, y);
    }
    __syncthreads();
    // ---- forward stage 2 (m=8) ----
    {
        float2 c[8], y[8];
        read8(lds, tid, c);
        __syncthreads();
        dft8<false>(c, y);
        stage8_write<false>(lds, tid, 3, y);
    }
    __syncthreads();
    // ---- forward stage 3 (m=64) ----
    {
        float2 c[8], y[8];
        read8(lds, tid, c);
        __syncthreads();
        dft8<false>(c, y);
        stage8_write<false>(lds, tid, 6, y);
    }
    __syncthreads();
    // ---- forward stage 4 (radix-4, m=512) fused with pointwise *Khat ----
    {
        float2 cc[2][4];
#pragma unroll
        for (int r = 0; r < 2; ++r)
#pragma unroll
            for (int s = 0; s < 4; ++s)
                cc[r][s] = lds[SW(tid + (r << 8) + (s << 9))];
        __syncthreads();
        const float2* kh = Khat + (size_t)h * kNFFT;
#pragma unroll
        for (int r = 0; r < 2; ++r) {
            int q = tid + (r << 8);
            float2 t0 = cadd(cc[r][0], cc[r][2]), t1 = csub(cc[r][0], cc[r][2]);
            float2 t2 = cadd(cc[r][1], cc[r][3]), t3 = csub(cc[r][1], cc[r][3]);
            float2 y0 = cadd(t0, t2);
            float2 y1 = make_float2(t1.x + t3.y, t1.y - t3.x);
            float2 y2 = csub(t0, t2);
            float2 y3 = make_float2(t1.x - t3.y, t1.y + t3.x);
            lds[SW(q)]        = cmul(y0, kh[q]);
            lds[SW(q + 512)]  = cmul(y1, kh[q + 512]);
            lds[SW(q + 1024)] = cmul(y2, kh[q + 1024]);
            lds[SW(q + 1536)] = cmul(y3, kh[q + 1536]);
        }
    }
    __syncthreads();
    // ---- inverse stage 1 (m=1) ----
    {
        float2 c[8], y[8];
        read8(lds, tid, c);
        __syncthreads();
        dft8<true>(c, y);
        stage8_write<true>(lds, tid, 0, y);
    }
    __syncthreads();
    // ---- inverse stage 2 (m=8) ----
    {
        float2 c[8], y[8];
        read8(lds, tid, c);
        __syncthreads();
        dft8<true>(c, y);
        stage8_write<true>(lds, tid, 3, y);
    }
    __syncthreads();
    // ---- inverse stage 3 (m=64) ----
    {
        float2 c[8], y[8];
        read8(lds, tid, c);
        __syncthreads();
        dft8<true>(c, y);
        stage8_write<true>(lds, tid, 6, y);
    }
    __syncthreads();
    // ---- inverse stage 4 (radix-4, m=512): only u=0,1 needed (l<1024),
    //      fused epilogue, registers -> global ----
    {
        float2 cc[2][4];
#pragma unroll
        for (int r = 0; r < 2; ++r)
#pragma unroll
            for (int s = 0; s < 4; ++s)
                cc[r][s] = lds[SW(tid + (r << 8) + (s << 9))];
        float Dh = Dvec[h];
        const float invn = 1.0f / (float)kNFFT;
#pragma unroll
        for (int r = 0; r < 2; ++r) {
            float2 t0 = cadd(cc[r][0], cc[r][2]), t1 = csub(cc[r][0], cc[r][2]);
            float2 t2 = cadd(cc[r][1], cc[r][3]), t3 = csub(cc[r][1], cc[r][3]);
            float2 y0 = cadd(t0, t2);                               // l = q
            float2 y1 = make_float2(t1.x - t3.y, t1.y + t3.x);      // l = q+512
            int l0 = tid + (r << 8);
            float2 u0 = us[r];
            float2 u1 = us[r + 2];
            rowa[l0]       = gelu_tanh(y0.x * invn + Dh * u0.x);
            rowb[l0]       = gelu_tanh(y0.y * invn + Dh * u0.y);
            rowa[l0 + 512] = gelu_tanh(y1.x * invn + Dh * u1.x);
            rowb[l0 + 512] = gelu_tanh(y1.y * invn + Dh * u1.y);
        }
    }
}

// ---------------------------------------------------------------------------
// Mean pool over L + fc. grid: (hb=16, b=32), 256 threads; atomicAdd partials.
// ---------------------------------------------------------------------------
__global__ __launch_bounds__(256) void final_kernel(const float* __restrict__ act,
                                                    const float* __restrict__ fc_w,
                                                    const float* __restrict__ fc_b,
                                                    float* __restrict__ out)
{
    int hb = blockIdx.x, b = blockIdx.y, tid = threadIdx.x;
    float acc = 0.f;
    for (int hh = 0; hh < 32; ++hh) {
        int h = hb * 32 + hh;
        float w = fc_w[h];
        const float* row = act + ((size_t)b * kH + h) * kL;
#pragma unroll
        for (int l = tid; l < kL; l += 256) acc += row[l] * w;
    }
    __shared__ float red[256];
    red[tid] = acc;
    __syncthreads();
    for (int s = 128; s > 0; s >>= 1) {
        if (tid < s) red[tid] += red[tid + s];
        __syncthreads();
    }
    if (tid == 0) {
        float v = red[0] * (1.0f / (float)kL);
        if (hb == 0) v += fc_b[0];
        atomicAdd(out + b, v);
    }
}

// ---------------------------------------------------------------------------
extern "C" void kernel_launch(void* const* d_in, const int* in_sizes, int n_in,
                              void* d_out, int out_size, void* d_ws, size_t ws_size,
                              hipStream_t stream)
{
    const int*   x         = (const int*)d_in[0];
    const float* embedding = (const float*)d_in[1];
    const float* log_dt    = (const float*)d_in[2];
    const float* A_log     = (const float*)d_in[3];
    const float* A_imag    = (const float*)d_in[4];
    const float* C_re      = (const float*)d_in[5];
    const float* C_im      = (const float*)d_in[6];
    const float* Dv        = (const float*)d_in[7];
    const float* fc_w      = (const float*)d_in[8];
    const float* fc_b      = (const float*)d_in[9];
    float* out = (float*)d_out;

    char* ws = (char*)d_ws;
    const size_t act_bytes = (size_t)kB * kH * kL * sizeof(float);   // 64 MiB
    float*  act  = (float*)ws;
    float2* Khat = (float2*)(ws + act_bytes);                        // 8 MiB

    hipMemsetAsync(d_out, 0, (size_t)out_size * sizeof(float), stream);
    embed_kernel<<<dim3(8, 16, 32), 256, 0, stream>>>(x, embedding, act);

    for (int layer = 0; layer < kNL; ++layer) {
        kcomp_kernel<<<kH, 256, 0, stream>>>(log_dt + layer * kH,
                                             A_log + (size_t)layer * kH * kN,
                                             A_imag + (size_t)layer * kH * kN,
                                             C_re + (size_t)layer * kH * kN,
                                             C_im + (size_t)layer * kH * kN,
                                             Khat);
        conv_kernel<<<dim3(kH, kB / 2), 256, 0, stream>>>(act, Khat, Dv + layer * kH);
    }

    final_kernel<<<dim3(16, kB), 256, 0, stream>>>(act, fc_w, fc_b, out);
}

// Round 3
// 389.203 us; speedup vs baseline: 1.8449x; 1.2310x over previous
//
#include <hip/hip_runtime.h>
#include <math.h>

// Problem constants
static const int kB = 32;
static const int kL = 1024;
static const int kH = 512;
static const int kN = 64;
static const int kNL = 4;
static const int kNFFT = 2048;

#define TWO_PI 6.283185307179586476925286766559

typedef float v2f __attribute__((ext_vector_type(2)));

// complex mul: (a.x b.x - a.y b.y, a.x b.y + a.y b.x)
__device__ __forceinline__ v2f cmul(v2f a, v2f b) {
    v2f axx = __builtin_shufflevector(a, a, 0, 0);
    v2f ayy = __builtin_shufflevector(a, a, 1, 1);
    v2f byx = __builtin_shufflevector(b, b, 1, 0);
    v2f t = ayy * byx;
    t.x = -t.x;
    return axx * b + t;     // v_pk_fma_f32
}

// j3 = fwd ? (t.y, -t.x) : (-t.y, t.x)
template<bool INV>
__device__ __forceinline__ v2f jrot(v2f t) {
    v2f r = __builtin_shufflevector(t, t, 1, 0);
    if (!INV) { r.y = -r.y; } else { r.x = -r.x; }
    return r;
}

// LDS swizzle: element i lives at i + (i>>4).  Read pattern tid+256s and all
// stage-write patterns decompose to base + compile-time offsets (see swoff).
#define LDSZ 2176
__device__ __forceinline__ constexpr int swoff(int LGM, int u) {
    return (LGM == 0) ? u : (LGM == 3) ? (8 * u + (u >> 1)) : (68 * u);
}

// ---------------------------------------------------------------------------
// 8-point DFT in registers, natural order. INV=true -> conjugate transform.
// ---------------------------------------------------------------------------
template<bool INV>
__device__ __forceinline__ void dft8(const v2f c[8], v2f y[8]) {
    const float s = 0.70710678118654752440f;
    v2f t0 = c[0] + c[4], t1 = c[0] - c[4];
    v2f t2 = c[2] + c[6], t3 = c[2] - c[6];
    v2f e0 = t0 + t2, e2 = t0 - t2;
    v2f j3 = jrot<INV>(t3);
    v2f e1 = t1 + j3, e3 = t1 - j3;

    t0 = c[1] + c[5]; t1 = c[1] - c[5];
    t2 = c[3] + c[7]; t3 = c[3] - c[7];
    v2f o0 = t0 + t2, o2 = t0 - t2;
    v2f j3o = jrot<INV>(t3);
    v2f o1 = t1 + j3o, o3 = t1 - j3o;

    if (!INV) {
        v2f r1 = __builtin_shufflevector(o1, o1, 1, 0);
        o1 = s * (v2f){o1.x + r1.x, o1.y - r1.y};          // s(x+y, y-x)
        v2f r2 = __builtin_shufflevector(o2, o2, 1, 0);
        o2 = (v2f){r2.x, -r2.y};                            // (y, -x)
        v2f r3 = __builtin_shufflevector(o3, o3, 1, 0);
        o3 = s * (v2f){r3.x - o3.x, -r3.y - o3.y};          // s(y-x, -(x+y))
    } else {
        v2f r1 = __builtin_shufflevector(o1, o1, 1, 0);
        o1 = s * (v2f){o1.x - r1.x, o1.y + r1.y};          // s(x-y, x+y)
        v2f r2 = __builtin_shufflevector(o2, o2, 1, 0);
        o2 = (v2f){-r2.x, r2.y};                            // (-y, x)
        v2f r3 = __builtin_shufflevector(o3, o3, 1, 0);
        o3 = s * (v2f){-(o3.x + r3.x), r3.y - o3.y};        // (-s(x+y), s(x-y))
    }
    y[0] = e0 + o0; y[4] = e0 - o0;
    y[1] = e1 + o1; y[5] = e1 - o1;
    y[2] = e2 + o2; y[6] = e2 - o2;
    y[3] = e3 + o3; y[7] = e3 - o3;
}

// Forward dft8 with inputs c[4..7] == 0 (zero-padded half).
__device__ __forceinline__ void dft8h(const v2f c[4], v2f y[8]) {
    const float s = 0.70710678118654752440f;
    v2f e0 = c[0] + c[2], e2 = c[0] - c[2];
    v2f j  = jrot<false>(c[2]);
    v2f e1 = c[0] + j, e3 = c[0] - j;
    v2f o0 = c[1] + c[3], o2 = c[1] - c[3];
    v2f jo = jrot<false>(c[3]);
    v2f o1 = c[1] + jo, o3 = c[1] - jo;

    v2f r1 = __builtin_shufflevector(o1, o1, 1, 0);
    o1 = s * (v2f){o1.x + r1.x, o1.y - r1.y};
    v2f r2 = __builtin_shufflevector(o2, o2, 1, 0);
    o2 = (v2f){r2.x, -r2.y};
    v2f r3 = __builtin_shufflevector(o3, o3, 1, 0);
    o3 = s * (v2f){r3.x - o3.x, -r3.y - o3.y};

    y[0] = e0 + o0; y[4] = e0 - o0;
    y[1] = e1 + o1; y[5] = e1 - o1;
    y[2] = e2 + o2; y[6] = e2 - o2;
    y[3] = e3 + o3; y[7] = e3 - o3;
}

// Stockham radix-8 stage: dst[j*8m + i + u*m] = W_N^{jm*u} * y[u]
template<bool INV, int LGM>
__device__ __forceinline__ void stage8_write(v2f* lds, int tid, v2f y[8]) {
    const int m = 1 << LGM;
    const int jm = tid & ~(m - 1);
    float ang = (INV ? (float)(TWO_PI / 2048.0) : -(float)(TWO_PI / 2048.0)) * (float)jm;
    float sn, cs;
    __sincosf(ang, &sn, &cs);
    v2f w1 = {cs, sn};
    v2f w2 = cmul(w1, w1);
    v2f w3 = cmul(w2, w1);
    v2f w4 = cmul(w2, w2);
    v2f w5 = cmul(w3, w2);
    v2f w6 = cmul(w3, w3);
    v2f w7 = cmul(w4, w3);
    int base = ((tid >> LGM) << (LGM + 3)) + (tid & (m - 1));
    int swb = base + (base >> 4);
    lds[swb + swoff(LGM, 0)] = y[0];
    lds[swb + swoff(LGM, 1)] = cmul(w1, y[1]);
    lds[swb + swoff(LGM, 2)] = cmul(w2, y[2]);
    lds[swb + swoff(LGM, 3)] = cmul(w3, y[3]);
    lds[swb + swoff(LGM, 4)] = cmul(w4, y[4]);
    lds[swb + swoff(LGM, 5)] = cmul(w5, y[5]);
    lds[swb + swoff(LGM, 6)] = cmul(w6, y[6]);
    lds[swb + swoff(LGM, 7)] = cmul(w7, y[7]);
}

__device__ __forceinline__ void read8(const v2f* lds, int swb, v2f c[8]) {
#pragma unroll
    for (int s = 0; s < 8; ++s) c[s] = lds[swb + 272 * s];
}

// gelu (tanh approx) on a pair: v*(1 - 1/(1+exp(2*0.79788456*(v+0.044715 v^3))))
__device__ __forceinline__ v2f gelu2(v2f v) {
    v2f v2 = v * v;
    v2f q = v2 * 0.044715f + 1.0f;
    v2f z = v * q * 1.5957691216057308f;
    v2f e;
    e.x = __expf(z.x); e.y = __expf(z.y);
    v2f den = e + 1.0f;
    v2f r;
    r.x = __builtin_amdgcn_rcpf(den.x);
    r.y = __builtin_amdgcn_rcpf(den.y);
    return v - v * r;
}

// ---------------------------------------------------------------------------
// Embedding gather with 64x64 tile transpose: act[b][h][l] = emb[x[b][l]][h]
// ---------------------------------------------------------------------------
__global__ __launch_bounds__(256) void embed_kernel(const int* __restrict__ x,
                                                    const float* __restrict__ emb,
                                                    float* __restrict__ act)
{
    __shared__ float tile[64][65];
    int hb = blockIdx.x, lb = blockIdx.y, b = blockIdx.z;
    int h0 = hb * 64, l0 = lb * 64;
    int tid = threadIdx.x;
#pragma unroll
    for (int k = 0; k < 16; ++k) {
        int idx = (k << 8) + tid;
        int li = idx >> 6, hi = idx & 63;
        int xv = x[b * kL + l0 + li];
        tile[li][hi] = emb[(size_t)xv * kH + h0 + hi];
    }
    __syncthreads();
#pragma unroll
    for (int k = 0; k < 16; ++k) {
        int idx = (k << 8) + tid;
        int hi = idx >> 6, li = idx & 63;
        act[((size_t)b * kH + h0 + hi) * kL + l0 + li] = tile[li][hi];
    }
}

// ---------------------------------------------------------------------------
// SSM kernel K[h][l] + forward FFT -> Khat (pre-scaled by 1/2048).
// grid: (h=512, layers_in_launch); layer = layer0 + blockIdx.y
// ---------------------------------------------------------------------------
__global__ __launch_bounds__(256) void kcomp_kernel(const float* __restrict__ log_dt,
                                                    const float* __restrict__ A_log,
                                                    const float* __restrict__ A_imag,
                                                    const float* __restrict__ C_re,
                                                    const float* __restrict__ C_im,
                                                    v2f* __restrict__ Khat,
                                                    int layer0, int out_stride)
{
    __shared__ v2f lds[LDSZ];
    __shared__ float dre_s[kN], dim_s[kN], g2re_s[kN], g2im_s[kN];

    int h = blockIdx.x, tid = threadIdx.x;
    int layer = layer0 + blockIdx.y;
    int swbase = tid + (tid >> 4);
    const size_t po = (size_t)layer * kH + h;

    if (tid < kN) {
        int n = tid;
        float dt  = expf(log_dt[po]);
        float Are = -expf(A_log[po * kN + n]);
        float Aim = A_imag[po * kN + n];
        float dre = dt * Are;
        float dim = dt * Aim;
        float er = expf(dre);
        float sw, cw;
        sincosf(dim, &sw, &cw);
        float emr = er * cw - 1.0f, emi = er * sw;
        float inv = 1.0f / (Are * Are + Aim * Aim);
        float air = Are * inv, aii = -Aim * inv;
        float br = emr * air - emi * aii;
        float bi = emr * aii + emi * air;
        float cr = C_re[po * kN + n], ci = C_im[po * kN + n];
        dre_s[n] = dre;
        dim_s[n] = dim;
        g2re_s[n] = 2.0f * (cr * br - ci * bi);
        g2im_s[n] = 2.0f * (cr * bi + ci * br);
    }
    __syncthreads();

    // K at l = tid + 256*s  (matches FFT stage-1 register layout)
    float acc0 = 0.f, acc1 = 0.f, acc2 = 0.f, acc3 = 0.f;
    for (int n = 0; n < kN; ++n) {
        float dre = dre_s[n], dim = dim_s[n];
        float g2re = g2re_s[n], g2im = g2im_s[n];
        float mag = expf(dre * (float)tid);
        double rev = (double)dim * (double)tid * (1.0 / TWO_PI);
        rev -= floor(rev);
        float th = (float)(rev * TWO_PI);
        float sp, cp;
        sincosf(th, &sp, &cp);
        float pzx = mag * cp, pzy = mag * sp;
        float mag256 = expf(dre * 256.0f);
        double rev2 = (double)dim * 256.0 * (1.0 / TWO_PI);
        rev2 -= floor(rev2);
        float th2 = (float)(rev2 * TWO_PI);
        float s2, c2;
        sincosf(th2, &s2, &c2);
        float wx = mag256 * c2, wy = mag256 * s2;

        float tx;
        acc0 += g2re * pzx - g2im * pzy;
        tx = pzx * wx - pzy * wy; pzy = pzx * wy + pzy * wx; pzx = tx;
        acc1 += g2re * pzx - g2im * pzy;
        tx = pzx * wx - pzy * wy; pzy = pzx * wy + pzy * wx; pzx = tx;
        acc2 += g2re * pzx - g2im * pzy;
        tx = pzx * wx - pzy * wy; pzy = pzx * wy + pzy * wx; pzx = tx;
        acc3 += g2re * pzx - g2im * pzy;
    }

    {   // forward stage 1 from registers (upper half zero)
        v2f c[4], y[8];
        c[0] = (v2f){acc0, 0.f}; c[1] = (v2f){acc1, 0.f};
        c[2] = (v2f){acc2, 0.f}; c[3] = (v2f){acc3, 0.f};
        dft8h(c, y);
        stage8_write<false, 0>(lds, tid, y);
    }
    __syncthreads();
    {
        v2f c[8], y[8];
        read8(lds, swbase, c);
        __syncthreads();
        dft8<false>(c, y);
        stage8_write<false, 3>(lds, tid, y);
    }
    __syncthreads();
    {
        v2f c[8], y[8];
        read8(lds, swbase, c);
        __syncthreads();
        dft8<false>(c, y);
        stage8_write<false, 6>(lds, tid, y);
    }
    __syncthreads();
    {   // radix-4 final stage (m=512, j=0) -> global, natural order, *1/2048
        const float invn = 1.0f / (float)kNFFT;
        v2f* outp = Khat + (size_t)(layer * out_stride + h) * kNFFT;
#pragma unroll
        for (int r = 0; r < 2; ++r) {
            v2f c0 = lds[swbase + 272 * r];
            v2f c1 = lds[swbase + 272 * r + 544];
            v2f c2 = lds[swbase + 272 * r + 1088];
            v2f c3 = lds[swbase + 272 * r + 1632];
            v2f t0 = c0 + c2, t1 = c0 - c2;
            v2f t2 = c1 + c3, t3 = c1 - c3;
            v2f j3 = jrot<false>(t3);
            int q = tid + (r << 8);
            outp[q]        = (t0 + t2) * invn;
            outp[q + 512]  = (t1 + j3) * invn;
            outp[q + 1024] = (t0 - t2) * invn;
            outp[q + 1536] = (t1 - j3) * invn;
        }
    }
}

// ---------------------------------------------------------------------------
// Conv layer (in-place): rows (2*pair,h),(2*pair+1,h) packed as one complex
// signal. Register radix-8 FFT, fused pointwise (Khat pre-scaled), epilogue.
// grid: (h=512, pair=16), 256 threads
// ---------------------------------------------------------------------------
__global__ __launch_bounds__(256) void conv_kernel(float* __restrict__ act,
                                                   const v2f* __restrict__ Khat,
                                                   const float* __restrict__ Dvec)
{
    __shared__ v2f lds[LDSZ];

    int h = blockIdx.x, pair = blockIdx.y, tid = threadIdx.x;
    int swbase = tid + (tid >> 4);
    float* rowa = act + ((size_t)(2 * pair) * kH + h) * kL;
    float* rowb = rowa + (size_t)kH * kL;

    v2f us[4];
#pragma unroll
    for (int s = 0; s < 4; ++s) {
        int l = tid + (s << 8);
        us[s] = (v2f){rowa[l], rowb[l]};
    }

    {   // fwd stage 1 (m=1), upper half zero
        v2f y[8];
        dft8h(us, y);
        stage8_write<false, 0>(lds, tid, y);
    }
    __syncthreads();
    {   // fwd stage 2 (m=8)
        v2f c[8], y[8];
        read8(lds, swbase, c);
        __syncthreads();
        dft8<false>(c, y);
        stage8_write<false, 3>(lds, tid, y);
    }
    __syncthreads();
    {   // fwd stage 3 (m=64)
        v2f c[8], y[8];
        read8(lds, swbase, c);
        __syncthreads();
        dft8<false>(c, y);
        stage8_write<false, 6>(lds, tid, y);
    }
    __syncthreads();
    {   // fwd stage 4 (radix-4, m=512) fused with pointwise *Khat
        v2f cc[2][4];
#pragma unroll
        for (int r = 0; r < 2; ++r)
#pragma unroll
            for (int s = 0; s < 4; ++s)
                cc[r][s] = lds[swbase + 272 * r + 544 * s];
        __syncthreads();
        const v2f* kh = Khat + (size_t)h * kNFFT;
#pragma unroll
        for (int r = 0; r < 2; ++r) {
            v2f t0 = cc[r][0] + cc[r][2], t1 = cc[r][0] - cc[r][2];
            v2f t2 = cc[r][1] + cc[r][3], t3 = cc[r][1] - cc[r][3];
            v2f j3 = jrot<false>(t3);
            int q = tid + (r << 8);
            int swq = swbase + 272 * r;
            lds[swq]        = cmul(t0 + t2, kh[q]);
            lds[swq + 544]  = cmul(t1 + j3, kh[q + 512]);
            lds[swq + 1088] = cmul(t0 - t2, kh[q + 1024]);
            lds[swq + 1632] = cmul(t1 - j3, kh[q + 1536]);
        }
    }
    __syncthreads();
    {   // inv stage 1 (m=1)
        v2f c[8], y[8];
        read8(lds, swbase, c);
        __syncthreads();
        dft8<true>(c, y);
        stage8_write<true, 0>(lds, tid, y);
    }
    __syncthreads();
    {   // inv stage 2 (m=8)
        v2f c[8], y[8];
        read8(lds, swbase, c);
        __syncthreads();
        dft8<true>(c, y);
        stage8_write<true, 3>(lds, tid, y);
    }
    __syncthreads();
    {   // inv stage 3 (m=64)
        v2f c[8], y[8];
        read8(lds, swbase, c);
        __syncthreads();
        dft8<true>(c, y);
        stage8_write<true, 6>(lds, tid, y);
    }
    __syncthreads();
    {   // inv stage 4 (radix-4, m=512): only l<1024 outputs; fused epilogue
        float Dh = Dvec[h];
#pragma unroll
        for (int r = 0; r < 2; ++r) {
            v2f c0 = lds[swbase + 272 * r];
            v2f c1 = lds[swbase + 272 * r + 544];
            v2f c2 = lds[swbase + 272 * r + 1088];
            v2f c3 = lds[swbase + 272 * r + 1632];
            v2f t0 = c0 + c2, t1 = c0 - c2;
            v2f t2 = c1 + c3, t3 = c1 - c3;
            v2f j3 = jrot<false>(t3);
            v2f y0 = t0 + t2;          // l = l0
            v2f y1 = t1 - j3;          // l = l0 + 512
            int l0 = tid + (r << 8);
            v2f g0 = gelu2(y0 + Dh * us[r]);
            v2f g1 = gelu2(y1 + Dh * us[r + 2]);
            rowa[l0]       = g0.x;
            rowb[l0]       = g0.y;
            rowa[l0 + 512] = g1.x;
            rowb[l0 + 512] = g1.y;
        }
    }
}

// ---------------------------------------------------------------------------
// Mean pool over L + fc. grid: (hb=16, b=32), 256 threads; atomicAdd partials.
// ---------------------------------------------------------------------------
__global__ __launch_bounds__(256) void final_kernel(const float* __restrict__ act,
                                                    const float* __restrict__ fc_w,
                                                    const float* __restrict__ fc_b,
                                                    float* __restrict__ out)
{
    int hb = blockIdx.x, b = blockIdx.y, tid = threadIdx.x;
    float acc = 0.f;
    for (int hh = 0; hh < 32; ++hh) {
        int h = hb * 32 + hh;
        float w = fc_w[h];
        const float* row = act + ((size_t)b * kH + h) * kL;
#pragma unroll
        for (int l = tid; l < kL; l += 256) acc += row[l] * w;
    }
    __shared__ float red[256];
    red[tid] = acc;
    __syncthreads();
    for (int s = 128; s > 0; s >>= 1) {
        if (tid < s) red[tid] += red[tid + s];
        __syncthreads();
    }
    if (tid == 0) {
        float v = red[0] * (1.0f / (float)kL);
        if (hb == 0) v += fc_b[0];
        atomicAdd(out + b, v);
    }
}

// ---------------------------------------------------------------------------
extern "C" void kernel_launch(void* const* d_in, const int* in_sizes, int n_in,
                              void* d_out, int out_size, void* d_ws, size_t ws_size,
                              hipStream_t stream)
{
    const int*   x         = (const int*)d_in[0];
    const float* embedding = (const float*)d_in[1];
    const float* log_dt    = (const float*)d_in[2];
    const float* A_log     = (const float*)d_in[3];
    const float* A_imag    = (const float*)d_in[4];
    const float* C_re      = (const float*)d_in[5];
    const float* C_im      = (const float*)d_in[6];
    const float* Dv        = (const float*)d_in[7];
    const float* fc_w      = (const float*)d_in[8];
    const float* fc_b      = (const float*)d_in[9];
    float* out = (float*)d_out;

    char* ws = (char*)d_ws;
    const size_t act_bytes  = (size_t)kB * kH * kL * sizeof(float);      // 64 MiB
    const size_t khat_bytes = (size_t)kH * kNFFT * sizeof(float) * 2;    // 8 MiB / layer
    float* act = (float*)ws;
    v2f*   Khat = (v2f*)(ws + act_bytes);

    const bool multi = ws_size >= act_bytes + kNL * khat_bytes;          // 96 MiB

    hipMemsetAsync(d_out, 0, (size_t)out_size * sizeof(float), stream);
    embed_kernel<<<dim3(8, 16, 32), 256, 0, stream>>>(x, embedding, act);

    if (multi) {
        // all 4 layers' Khat in one launch (weights-only dependency)
        kcomp_kernel<<<dim3(kH, kNL), 256, 0, stream>>>(log_dt, A_log, A_imag,
                                                        C_re, C_im, Khat, 0, kH);
        for (int layer = 0; layer < kNL; ++layer) {
            conv_kernel<<<dim3(kH, kB / 2), 256, 0, stream>>>(
                act, Khat + (size_t)layer * kH * kNFFT, Dv + layer * kH);
        }
    } else {
        for (int layer = 0; layer < kNL; ++layer) {
            kcomp_kernel<<<dim3(kH, 1), 256, 0, stream>>>(log_dt, A_log, A_imag,
                                                          C_re, C_im, Khat, layer, 0);
            conv_kernel<<<dim3(kH, kB / 2), 256, 0, stream>>>(act, Khat, Dv + layer * kH);
        }
    }

    final_kernel<<<dim3(16, kB), 256, 0, stream>>>(act, fc_w, fc_b, out);
}

// Round 4
// 334.647 us; speedup vs baseline: 2.1457x; 1.1630x over previous
//
#include <hip/hip_runtime.h>
#include <math.h>

// Problem constants
static const int kB = 32;
static const int kL = 1024;
static const int kH = 512;
static const int kN = 64;
static const int kNL = 4;
static const int kNFFT = 2048;

#define TWO_PI 6.283185307179586476925286766559

typedef float v2f __attribute__((ext_vector_type(2)));

// complex mul: (a.x b.x - a.y b.y, a.x b.y + a.y b.x)
__device__ __forceinline__ v2f cmul(v2f a, v2f b) {
    v2f axx = __builtin_shufflevector(a, a, 0, 0);
    v2f ayy = __builtin_shufflevector(a, a, 1, 1);
    v2f byx = __builtin_shufflevector(b, b, 1, 0);
    v2f t = ayy * byx;
    t.x = -t.x;
    return axx * b + t;     // v_pk_fma_f32
}

// j3 = fwd ? (t.y, -t.x) : (-t.y, t.x)
template<bool INV>
__device__ __forceinline__ v2f jrot(v2f t) {
    v2f r = __builtin_shufflevector(t, t, 1, 0);
    if (!INV) { r.y = -r.y; } else { r.x = -r.x; }
    return r;
}

// LDS swizzle: element i lives at i + (i>>4).  Read pattern tid+256s and all
// stage-write patterns decompose to base + compile-time offsets (see swoff).
#define LDSZ 2176
__device__ __forceinline__ constexpr int swoff(int LGM, int u) {
    return (LGM == 0) ? u : (LGM == 3) ? (8 * u + (u >> 1)) : (68 * u);
}

// ---------------------------------------------------------------------------
// 8-point DFT in registers, natural order. INV=true -> conjugate transform.
// ---------------------------------------------------------------------------
template<bool INV>
__device__ __forceinline__ void dft8(const v2f c[8], v2f y[8]) {
    const float s = 0.70710678118654752440f;
    v2f t0 = c[0] + c[4], t1 = c[0] - c[4];
    v2f t2 = c[2] + c[6], t3 = c[2] - c[6];
    v2f e0 = t0 + t2, e2 = t0 - t2;
    v2f j3 = jrot<INV>(t3);
    v2f e1 = t1 + j3, e3 = t1 - j3;

    t0 = c[1] + c[5]; t1 = c[1] - c[5];
    t2 = c[3] + c[7]; t3 = c[3] - c[7];
    v2f o0 = t0 + t2, o2 = t0 - t2;
    v2f j3o = jrot<INV>(t3);
    v2f o1 = t1 + j3o, o3 = t1 - j3o;

    if (!INV) {
        v2f r1 = __builtin_shufflevector(o1, o1, 1, 0);
        o1 = s * (v2f){o1.x + r1.x, o1.y - r1.y};          // s(x+y, y-x)
        v2f r2 = __builtin_shufflevector(o2, o2, 1, 0);
        o2 = (v2f){r2.x, -r2.y};                            // (y, -x)
        v2f r3 = __builtin_shufflevector(o3, o3, 1, 0);
        o3 = s * (v2f){r3.x - o3.x, -r3.y - o3.y};          // s(y-x, -(x+y))
    } else {
        v2f r1 = __builtin_shufflevector(o1, o1, 1, 0);
        o1 = s * (v2f){o1.x - r1.x, o1.y + r1.y};          // s(x-y, x+y)
        v2f r2 = __builtin_shufflevector(o2, o2, 1, 0);
        o2 = (v2f){-r2.x, r2.y};                            // (-y, x)
        v2f r3 = __builtin_shufflevector(o3, o3, 1, 0);
        o3 = s * (v2f){-(o3.x + r3.x), r3.y - o3.y};        // (-s(x+y), s(x-y))
    }
    y[0] = e0 + o0; y[4] = e0 - o0;
    y[1] = e1 + o1; y[5] = e1 - o1;
    y[2] = e2 + o2; y[6] = e2 - o2;
    y[3] = e3 + o3; y[7] = e3 - o3;
}

// Forward dft8 with inputs c[4..7] == 0 (zero-padded half).
__device__ __forceinline__ void dft8h(const v2f c[4], v2f y[8]) {
    const float s = 0.70710678118654752440f;
    v2f e0 = c[0] + c[2], e2 = c[0] - c[2];
    v2f j  = jrot<false>(c[2]);
    v2f e1 = c[0] + j, e3 = c[0] - j;
    v2f o0 = c[1] + c[3], o2 = c[1] - c[3];
    v2f jo = jrot<false>(c[3]);
    v2f o1 = c[1] + jo, o3 = c[1] - jo;

    v2f r1 = __builtin_shufflevector(o1, o1, 1, 0);
    o1 = s * (v2f){o1.x + r1.x, o1.y - r1.y};
    v2f r2 = __builtin_shufflevector(o2, o2, 1, 0);
    o2 = (v2f){r2.x, -r2.y};
    v2f r3 = __builtin_shufflevector(o3, o3, 1, 0);
    o3 = s * (v2f){r3.x - o3.x, -r3.y - o3.y};

    y[0] = e0 + o0; y[4] = e0 - o0;
    y[1] = e1 + o1; y[5] = e1 - o1;
    y[2] = e2 + o2; y[6] = e2 - o2;
    y[3] = e3 + o3; y[7] = e3 - o3;
}

// Stockham radix-8 stage: dst[j*8m + i + u*m] = W_N^{jm*u} * y[u]
// Twiddle base angle in REVOLUTIONS fed straight to v_sin/v_cos.
template<bool INV, int LGM>
__device__ __forceinline__ void stage8_write(v2f* lds, int tid, v2f y[8]) {
    const int m = 1 << LGM;
    const int jm = tid & ~(m - 1);
    float rev = (INV ? (1.0f / 2048.0f) : (-1.0f / 2048.0f)) * (float)jm;
    v2f w1 = { __builtin_amdgcn_cosf(rev), __builtin_amdgcn_sinf(rev) };
    v2f w2 = cmul(w1, w1);
    v2f w3 = cmul(w2, w1);
    v2f w4 = cmul(w2, w2);
    v2f w5 = cmul(w3, w2);
    v2f w6 = cmul(w3, w3);
    v2f w7 = cmul(w4, w3);
    int base = ((tid >> LGM) << (LGM + 3)) + (tid & (m - 1));
    int swb = base + (base >> 4);
    lds[swb + swoff(LGM, 0)] = y[0];
    lds[swb + swoff(LGM, 1)] = cmul(w1, y[1]);
    lds[swb + swoff(LGM, 2)] = cmul(w2, y[2]);
    lds[swb + swoff(LGM, 3)] = cmul(w3, y[3]);
    lds[swb + swoff(LGM, 4)] = cmul(w4, y[4]);
    lds[swb + swoff(LGM, 5)] = cmul(w5, y[5]);
    lds[swb + swoff(LGM, 6)] = cmul(w6, y[6]);
    lds[swb + swoff(LGM, 7)] = cmul(w7, y[7]);
}

__device__ __forceinline__ void read8(const v2f* lds, int swb, v2f c[8]) {
#pragma unroll
    for (int s = 0; s < 8; ++s) c[s] = lds[swb + 272 * s];
}

// gelu (tanh approx) on a pair: v*(1 - 1/(1+exp(2*0.79788456*(v+0.044715 v^3))))
__device__ __forceinline__ v2f gelu2(v2f v) {
    v2f v2 = v * v;
    v2f q = v2 * 0.044715f + 1.0f;
    v2f z = v * q * 1.5957691216057308f;
    v2f e;
    e.x = __expf(z.x); e.y = __expf(z.y);
    v2f den = e + 1.0f;
    v2f r;
    r.x = __builtin_amdgcn_rcpf(den.x);
    r.y = __builtin_amdgcn_rcpf(den.y);
    return v - v * r;
}

// ---------------------------------------------------------------------------
// Embedding gather with 64x64 tile transpose: act[b][h][l] = emb[x[b][l]][h]
// ---------------------------------------------------------------------------
__global__ __launch_bounds__(256) void embed_kernel(const int* __restrict__ x,
                                                    const float* __restrict__ emb,
                                                    float* __restrict__ act)
{
    __shared__ float tile[64][65];
    int hb = blockIdx.x, lb = blockIdx.y, b = blockIdx.z;
    int h0 = hb * 64, l0 = lb * 64;
    int tid = threadIdx.x;
#pragma unroll
    for (int k = 0; k < 16; ++k) {
        int idx = (k << 8) + tid;
        int li = idx >> 6, hi = idx & 63;
        int xv = x[b * kL + l0 + li];
        tile[li][hi] = emb[(size_t)xv * kH + h0 + hi];
    }
    __syncthreads();
#pragma unroll
    for (int k = 0; k < 16; ++k) {
        int idx = (k << 8) + tid;
        int hi = idx >> 6, li = idx & 63;
        act[((size_t)b * kH + h0 + hi) * kL + l0 + li] = tile[li][hi];
    }
}

// ---------------------------------------------------------------------------
// SSM kernel K[h][l] + forward FFT -> Khat (pre-scaled by 1/2048).
// Fast path: phase in revolutions, exact f32 hi/lo split (hi*l exact for
// l<1024 since hi has 12 mantissa bits), v_sin/v_cos take revolutions.
// grid: (h=512, layers); layer = layer0 + blockIdx.y
// ---------------------------------------------------------------------------
__global__ __launch_bounds__(256) void kcomp_kernel(const float* __restrict__ log_dt,
                                                    const float* __restrict__ A_log,
                                                    const float* __restrict__ A_imag,
                                                    const float* __restrict__ C_re,
                                                    const float* __restrict__ C_im,
                                                    v2f* __restrict__ Khat,
                                                    int layer0, int out_stride)
{
    __shared__ v2f lds[LDSZ];
    __shared__ float dre_s[kN], g2re_s[kN], g2im_s[kN], hi_s[kN], lo_s[kN];
    __shared__ v2f w256_s[kN];

    int h = blockIdx.x, tid = threadIdx.x;
    int layer = layer0 + blockIdx.y;
    int swbase = tid + (tid >> 4);
    const size_t po = (size_t)layer * kH + h;

    if (tid < kN) {
        int n = tid;
        float dt  = expf(log_dt[po]);
        float Are = -expf(A_log[po * kN + n]);
        float Aim = A_imag[po * kN + n];
        float dre = dt * Are;
        float dim = dt * Aim;
        float er = expf(dre);
        float sw, cw;
        sincosf(dim, &sw, &cw);
        float emr = er * cw - 1.0f, emi = er * sw;
        float inv = 1.0f / (Are * Are + Aim * Aim);
        float air = Are * inv, aii = -Aim * inv;
        float br = emr * air - emi * aii;
        float bi = emr * aii + emi * air;
        float cr = C_re[po * kN + n], ci = C_im[po * kN + n];
        dre_s[n]  = dre;
        g2re_s[n] = 2.0f * (cr * br - ci * bi);
        g2im_s[n] = 2.0f * (cr * bi + ci * br);
        // phase step in revolutions, hi/lo split (hi: 12 mantissa bits)
        double dimrev = (double)dim * (1.0 / TWO_PI);
        float drf = (float)dimrev;
        float hi = __uint_as_float(__float_as_uint(drf) & 0xFFFFF000u);
        hi_s[n] = hi;
        lo_s[n] = (float)(dimrev - (double)hi);
        // thread-invariant 256-step multiplier
        float mag256 = __expf(dre * 256.0f);
        double r2 = dimrev * 256.0;
        r2 -= floor(r2);
        float fr2 = (float)r2;
        w256_s[n] = (v2f){mag256 * __builtin_amdgcn_cosf(fr2),
                          mag256 * __builtin_amdgcn_sinf(fr2)};
    }
    __syncthreads();

    // K at l = tid + 256*s  (matches FFT stage-1 register layout)
    float acc0 = 0.f, acc1 = 0.f, acc2 = 0.f, acc3 = 0.f;
    const float lf = (float)tid;
    for (int n = 0; n < kN; ++n) {
        float dre  = dre_s[n];
        float g2re = g2re_s[n], g2im = g2im_s[n];
        float t1 = hi_s[n] * lf;            // exact
        float r1 = t1 - floorf(t1);
        float rv = r1 + lo_s[n] * lf;
        rv -= floorf(rv);                   // revolutions in [0,1)
        float mag = __expf(dre * lf);
        float sp = __builtin_amdgcn_sinf(rv);
        float cp = __builtin_amdgcn_cosf(rv);
        float pzx = mag * cp, pzy = mag * sp;
        v2f w = w256_s[n];
        float tx;
        acc0 += g2re * pzx - g2im * pzy;
        tx = pzx * w.x - pzy * w.y; pzy = pzx * w.y + pzy * w.x; pzx = tx;
        acc1 += g2re * pzx - g2im * pzy;
        tx = pzx * w.x - pzy * w.y; pzy = pzx * w.y + pzy * w.x; pzx = tx;
        acc2 += g2re * pzx - g2im * pzy;
        tx = pzx * w.x - pzy * w.y; pzy = pzx * w.y + pzy * w.x; pzx = tx;
        acc3 += g2re * pzx - g2im * pzy;
    }

    {   // forward stage 1 from registers (upper half zero)
        v2f c[4], y[8];
        c[0] = (v2f){acc0, 0.f}; c[1] = (v2f){acc1, 0.f};
        c[2] = (v2f){acc2, 0.f}; c[3] = (v2f){acc3, 0.f};
        dft8h(c, y);
        stage8_write<false, 0>(lds, tid, y);
    }
    __syncthreads();
    {
        v2f c[8], y[8];
        read8(lds, swbase, c);
        __syncthreads();
        dft8<false>(c, y);
        stage8_write<false, 3>(lds, tid, y);
    }
    __syncthreads();
    {
        v2f c[8], y[8];
        read8(lds, swbase, c);
        __syncthreads();
        dft8<false>(c, y);
        stage8_write<false, 6>(lds, tid, y);
    }
    __syncthreads();
    {   // radix-4 final stage (m=512, j=0) -> global, natural order, *1/2048
        const float invn = 1.0f / (float)kNFFT;
        v2f* outp = Khat + (size_t)(layer * out_stride + h) * kNFFT;
#pragma unroll
        for (int r = 0; r < 2; ++r) {
            v2f c0 = lds[swbase + 272 * r];
            v2f c1 = lds[swbase + 272 * r + 544];
            v2f c2 = lds[swbase + 272 * r + 1088];
            v2f c3 = lds[swbase + 272 * r + 1632];
            v2f t0 = c0 + c2, t1 = c0 - c2;
            v2f t2 = c1 + c3, t3 = c1 - c3;
            v2f j3 = jrot<false>(t3);
            int q = tid + (r << 8);
            outp[q]        = (t0 + t2) * invn;
            outp[q + 512]  = (t1 + j3) * invn;
            outp[q + 1024] = (t0 - t2) * invn;
            outp[q + 1536] = (t1 - j3) * invn;
        }
    }
}

// ---------------------------------------------------------------------------
// Fused 4-layer conv + mean-pool + fc.  Each wg owns rows (2*pair,h) and
// (2*pair+1,h) packed as one complex signal, kept in registers across all
// layers.  Per layer: FFT -> *Khat_l -> IFFT -> +D*u -> gelu (in regs).
// After layer 3: block-reduce the row sums, scale by fc_w[h]/L, atomicAdd.
// grid: (h=512, pair=16), 256 threads
// ---------------------------------------------------------------------------
__global__ __launch_bounds__(256) void conv_mega(const float* __restrict__ act,
                                                 const v2f* __restrict__ Khat,
                                                 const float* __restrict__ Dvec,
                                                 const float* __restrict__ fc_w,
                                                 const float* __restrict__ fc_b,
                                                 float* __restrict__ out)
{
    __shared__ v2f lds[LDSZ];
    __shared__ v2f wred[4];

    int h = blockIdx.x, pair = blockIdx.y, tid = threadIdx.x;
    int swbase = tid + (tid >> 4);
    const float* rowa = act + ((size_t)(2 * pair) * kH + h) * kL;
    const float* rowb = rowa + (size_t)kH * kL;

    v2f us[4];
#pragma unroll
    for (int s = 0; s < 4; ++s) {
        int l = tid + (s << 8);
        us[s] = (v2f){rowa[l], rowb[l]};
    }

#pragma unroll 1
    for (int layer = 0; layer < kNL; ++layer) {
        const v2f* kh = Khat + ((size_t)layer * kH + h) * kNFFT;
        float Dh = Dvec[layer * kH + h];

        {   // fwd stage 1 (m=1), upper half zero
            v2f y[8];
            dft8h(us, y);
            stage8_write<false, 0>(lds, tid, y);
        }
        __syncthreads();
        {   // fwd stage 2 (m=8)
            v2f c[8], y[8];
            read8(lds, swbase, c);
            __syncthreads();
            dft8<false>(c, y);
            stage8_write<false, 3>(lds, tid, y);
        }
        __syncthreads();
        {   // fwd stage 3 (m=64)
            v2f c[8], y[8];
            read8(lds, swbase, c);
            __syncthreads();
            dft8<false>(c, y);
            stage8_write<false, 6>(lds, tid, y);
        }
        __syncthreads();
        {   // fwd stage 4 (radix-4, m=512) fused with pointwise *Khat
            v2f cc[2][4];
#pragma unroll
            for (int r = 0; r < 2; ++r)
#pragma unroll
                for (int s = 0; s < 4; ++s)
                    cc[r][s] = lds[swbase + 272 * r + 544 * s];
            __syncthreads();
#pragma unroll
            for (int r = 0; r < 2; ++r) {
                v2f t0 = cc[r][0] + cc[r][2], t1 = cc[r][0] - cc[r][2];
                v2f t2 = cc[r][1] + cc[r][3], t3 = cc[r][1] - cc[r][3];
                v2f j3 = jrot<false>(t3);
                int q = tid + (r << 8);
                int swq = swbase + 272 * r;
                lds[swq]        = cmul(t0 + t2, kh[q]);
                lds[swq + 544]  = cmul(t1 + j3, kh[q + 512]);
                lds[swq + 1088] = cmul(t0 - t2, kh[q + 1024]);
                lds[swq + 1632] = cmul(t1 - j3, kh[q + 1536]);
            }
        }
        __syncthreads();
        {   // inv stage 1 (m=1)
            v2f c[8], y[8];
            read8(lds, swbase, c);
            __syncthreads();
            dft8<true>(c, y);
            stage8_write<true, 0>(lds, tid, y);
        }
        __syncthreads();
        {   // inv stage 2 (m=8)
            v2f c[8], y[8];
            read8(lds, swbase, c);
            __syncthreads();
            dft8<true>(c, y);
            stage8_write<true, 3>(lds, tid, y);
        }
        __syncthreads();
        {   // inv stage 3 (m=64)
            v2f c[8], y[8];
            read8(lds, swbase, c);
            __syncthreads();
            dft8<true>(c, y);
            stage8_write<true, 6>(lds, tid, y);
        }
        __syncthreads();
        {   // inv stage 4 (radix-4, m=512): l<1024 only; +D*u; gelu -> regs
            v2f cc[2][4];
#pragma unroll
            for (int r = 0; r < 2; ++r)
#pragma unroll
                for (int s = 0; s < 4; ++s)
                    cc[r][s] = lds[swbase + 272 * r + 544 * s];
#pragma unroll
            for (int r = 0; r < 2; ++r) {
                v2f t0 = cc[r][0] + cc[r][2], t1 = cc[r][0] - cc[r][2];
                v2f t2 = cc[r][1] + cc[r][3], t3 = cc[r][1] - cc[r][3];
                v2f j3 = jrot<false>(t3);
                v2f y0 = t0 + t2;          // l = tid + 256r
                v2f y1 = t1 - j3;          // l = tid + 256r + 512
                us[r]     = gelu2(y0 + Dh * us[r]);
                us[r + 2] = gelu2(y1 + Dh * us[r + 2]);
            }
        }
        __syncthreads();   // protect inv-4 reads before next layer's writes
    }

    // ---- pooled fc: partial = sum over this thread's 4 l-slots ----
    v2f p = us[0] + us[1] + us[2] + us[3];
#pragma unroll
    for (int off = 32; off > 0; off >>= 1) {
        p.x += __shfl_down(p.x, off);
        p.y += __shfl_down(p.y, off);
    }
    if ((tid & 63) == 0) wred[tid >> 6] = p;
    __syncthreads();
    if (tid == 0) {
        v2f t = wred[0] + wred[1] + wred[2] + wred[3];
        float scale = fc_w[h] * (1.0f / (float)kL);
        float bias = (h == 0) ? fc_b[0] : 0.0f;
        atomicAdd(out + 2 * pair,     t.x * scale + bias);
        atomicAdd(out + 2 * pair + 1, t.y * scale + bias);
    }
}

// ---------------------------------------------------------------------------
// Fallback path kernels (ws too small for all-layer Khat): per-layer conv
// writing act in place, then pool+fc.
// ---------------------------------------------------------------------------
__global__ __launch_bounds__(256) void conv_kernel(float* __restrict__ act,
                                                   const v2f* __restrict__ Khat,
                                                   const float* __restrict__ Dvec)
{
    __shared__ v2f lds[LDSZ];

    int h = blockIdx.x, pair = blockIdx.y, tid = threadIdx.x;
    int swbase = tid + (tid >> 4);
    float* rowa = act + ((size_t)(2 * pair) * kH + h) * kL;
    float* rowb = rowa + (size_t)kH * kL;

    v2f us[4];
#pragma unroll
    for (int s = 0; s < 4; ++s) {
        int l = tid + (s << 8);
        us[s] = (v2f){rowa[l], rowb[l]};
    }
    {
        v2f y[8];
        dft8h(us, y);
        stage8_write<false, 0>(lds, tid, y);
    }
    __syncthreads();
    {
        v2f c[8], y[8];
        read8(lds, swbase, c);
        __syncthreads();
        dft8<false>(c, y);
        stage8_write<false, 3>(lds, tid, y);
    }
    __syncthreads();
    {
        v2f c[8], y[8];
        read8(lds, swbase, c);
        __syncthreads();
        dft8<false>(c, y);
        stage8_write<false, 6>(lds, tid, y);
    }
    __syncthreads();
    {
        v2f cc[2][4];
#pragma unroll
        for (int r = 0; r < 2; ++r)
#pragma unroll
            for (int s = 0; s < 4; ++s)
                cc[r][s] = lds[swbase + 272 * r + 544 * s];
        __syncthreads();
        const v2f* kh = Khat + (size_t)h * kNFFT;
#pragma unroll
        for (int r = 0; r < 2; ++r) {
            v2f t0 = cc[r][0] + cc[r][2], t1 = cc[r][0] - cc[r][2];
            v2f t2 = cc[r][1] + cc[r][3], t3 = cc[r][1] - cc[r][3];
            v2f j3 = jrot<false>(t3);
            int q = tid + (r << 8);
            int swq = swbase + 272 * r;
            lds[swq]        = cmul(t0 + t2, kh[q]);
            lds[swq + 544]  = cmul(t1 + j3, kh[q + 512]);
            lds[swq + 1088] = cmul(t0 - t2, kh[q + 1024]);
            lds[swq + 1632] = cmul(t1 - j3, kh[q + 1536]);
        }
    }
    __syncthreads();
    {
        v2f c[8], y[8];
        read8(lds, swbase, c);
        __syncthreads();
        dft8<true>(c, y);
        stage8_write<true, 0>(lds, tid, y);
    }
    __syncthreads();
    {
        v2f c[8], y[8];
        read8(lds, swbase, c);
        __syncthreads();
        dft8<true>(c, y);
        stage8_write<true, 3>(lds, tid, y);
    }
    __syncthreads();
    {
        v2f c[8], y[8];
        read8(lds, swbase, c);
        __syncthreads();
        dft8<true>(c, y);
        stage8_write<true, 6>(lds, tid, y);
    }
    __syncthreads();
    {
        float Dh = Dvec[h];
#pragma unroll
        for (int r = 0; r < 2; ++r) {
            v2f c0 = lds[swbase + 272 * r];
            v2f c1 = lds[swbase + 272 * r + 544];
            v2f c2 = lds[swbase + 272 * r + 1088];
            v2f c3 = lds[swbase + 272 * r + 1632];
            v2f t0 = c0 + c2, t1 = c0 - c2;
            v2f t2 = c1 + c3, t3 = c1 - c3;
            v2f j3 = jrot<false>(t3);
            v2f y0 = t0 + t2;
            v2f y1 = t1 - j3;
            int l0 = tid + (r << 8);
            v2f g0 = gelu2(y0 + Dh * us[r]);
            v2f g1 = gelu2(y1 + Dh * us[r + 2]);
            rowa[l0]       = g0.x;
            rowb[l0]       = g0.y;
            rowa[l0 + 512] = g1.x;
            rowb[l0 + 512] = g1.y;
        }
    }
}

__global__ __launch_bounds__(256) void final_kernel(const float* __restrict__ act,
                                                    const float* __restrict__ fc_w,
                                                    const float* __restrict__ fc_b,
                                                    float* __restrict__ out)
{
    int hb = blockIdx.x, b = blockIdx.y, tid = threadIdx.x;
    float acc = 0.f;
    for (int hh = 0; hh < 32; ++hh) {
        int h = hb * 32 + hh;
        float w = fc_w[h];
        const float* row = act + ((size_t)b * kH + h) * kL;
#pragma unroll
        for (int l = tid; l < kL; l += 256) acc += row[l] * w;
    }
    __shared__ float red[256];
    red[tid] = acc;
    __syncthreads();
    for (int s = 128; s > 0; s >>= 1) {
        if (tid < s) red[tid] += red[tid + s];
        __syncthreads();
    }
    if (tid == 0) {
        float v = red[0] * (1.0f / (float)kL);
        if (hb == 0) v += fc_b[0];
        atomicAdd(out + b, v);
    }
}

// ---------------------------------------------------------------------------
extern "C" void kernel_launch(void* const* d_in, const int* in_sizes, int n_in,
                              void* d_out, int out_size, void* d_ws, size_t ws_size,
                              hipStream_t stream)
{
    const int*   x         = (const int*)d_in[0];
    const float* embedding = (const float*)d_in[1];
    const float* log_dt    = (const float*)d_in[2];
    const float* A_log     = (const float*)d_in[3];
    const float* A_imag    = (const float*)d_in[4];
    const float* C_re      = (const float*)d_in[5];
    const float* C_im      = (const float*)d_in[6];
    const float* Dv        = (const float*)d_in[7];
    const float* fc_w      = (const float*)d_in[8];
    const float* fc_b      = (const float*)d_in[9];
    float* out = (float*)d_out;

    char* ws = (char*)d_ws;
    const size_t act_bytes  = (size_t)kB * kH * kL * sizeof(float);      // 64 MiB
    const size_t khat_bytes = (size_t)kH * kNFFT * sizeof(float) * 2;    // 8 MiB / layer
    float* act = (float*)ws;
    v2f*   Khat = (v2f*)(ws + act_bytes);

    const bool multi = ws_size >= act_bytes + kNL * khat_bytes;          // 96 MiB

    hipMemsetAsync(d_out, 0, (size_t)out_size * sizeof(float), stream);
    embed_kernel<<<dim3(8, 16, 32), 256, 0, stream>>>(x, embedding, act);

    if (multi) {
        kcomp_kernel<<<dim3(kH, kNL), 256, 0, stream>>>(log_dt, A_log, A_imag,
                                                        C_re, C_im, Khat, 0, kH);
        conv_mega<<<dim3(kH, kB / 2), 256, 0, stream>>>(act, Khat, Dv,
                                                        fc_w, fc_b, out);
    } else {
        for (int layer = 0; layer < kNL; ++layer) {
            kcomp_kernel<<<dim3(kH, 1), 256, 0, stream>>>(log_dt, A_log, A_imag,
                                                          C_re, C_im, Khat, layer, 0);
            conv_kernel<<<dim3(kH, kB / 2), 256, 0, stream>>>(act, Khat, Dv + layer * kH);
        }
        final_kernel<<<dim3(16, kB), 256, 0, stream>>>(act, fc_w, fc_b, out);
    }
}